// Round 15
// baseline (600.023 us; speedup 1.0000x reference)
//
#include <hip/hip_runtime.h>
#include <hip/hip_bf16.h>
#include <stdint.h>

typedef _Float16 half8 __attribute__((ext_vector_type(8)));
typedef float float4v __attribute__((ext_vector_type(4)));

#define K_ 20
#define KCH 12
#define NCHUNK 4
#define CHSZ 2048
#define NTOT 32768        // B*N rows
#define ROWS 655360       // NTOT*K_

__device__ __forceinline__ unsigned encf(float v) {
    unsigned u = __float_as_uint(v);
    return ((int)u < 0) ? ~u : (u | 0x80000000u);
}

// 12-deep sorted-insert (ascending keys), fully register-resident
__device__ __forceinline__ void ins12(unsigned* lst, unsigned key) {
    bool chi = key < lst[11];
#pragma unroll
    for (int j = 11; j >= 1; --j) {
        bool clo = key < lst[j - 1];
        lst[j] = clo ? lst[j - 1] : (chi ? key : lst[j]);
        chi = clo;
    }
    lst[0] = chi ? key : lst[0];
}

// ---- transpose x (B,C,N) -> f fp32 + fh fp16 + numpy-bit-exact sq ----
// sq: numpy pairwise_sum scalar 8-accumulator branch (r4-verified, DO NOT TOUCH)
// FUSED: blocks >= 512 run the old k_prep (fp16 weight tiles).
__global__ void __launch_bounds__(256) k_transpose(const float* __restrict__ x,
                                                   float* __restrict__ f,
                                                   _Float16* __restrict__ fh,
                                                   float* __restrict__ sq,
                                                   const float* __restrict__ W1,
                                                   const float* __restrict__ W2,
                                                   _Float16* __restrict__ w1d_h,
                                                   _Float16* __restrict__ wcd_h,
                                                   _Float16* __restrict__ w2_h) {
    __shared__ float tile[64][65];
    int blk = blockIdx.x;              // 0..527
    if (blk >= 512) {                  // fused k_prep: 16 blocks
        int i = (blk - 512) * 256 + threadIdx.x;   // 0..4095
        int o = i >> 6, c = i & 63;
        w1d_h[i] = (_Float16)W1[o * 128 + c];
        wcd_h[i] = (_Float16)(W1[o * 128 + 64 + c] - W1[o * 128 + c]);
        w2_h[i]  = (_Float16)W2[i];
        return;
    }
    int b = blk >> 7, nt = blk & 127;
    int r = threadIdx.x >> 6, j = threadIdx.x & 63;
    const float* xb = x + ((size_t)b * 64) * 8192 + nt * 64;
#pragma unroll
    for (int i = 0; i < 16; ++i) {
        int c = i * 4 + r;
        tile[c][j] = xb[(size_t)c * 8192 + j];
    }
    __syncthreads();
    size_t nbase = (size_t)(b * 8192 + nt * 64);
    float* fb = f + nbase * 64;
    _Float16* fhb = fh + nbase * 64;
#pragma unroll
    for (int i = 0; i < 16; ++i) {
        int n = i * 4 + r;
        float v = tile[j][n];
        fb[(size_t)n * 64 + j] = v;
        fhb[(size_t)n * 64 + j] = (_Float16)v;
    }
    if (r == 0) {
#pragma clang fp contract(off)
        float p[64];
#pragma unroll
        for (int c = 0; c < 64; ++c) { float v = tile[c][j]; p[c] = v * v; }
        float rr[8];
#pragma unroll
        for (int q = 0; q < 8; ++q) rr[q] = p[q];
#pragma unroll
        for (int i = 8; i < 64; i += 8) {
#pragma unroll
            for (int q = 0; q < 8; ++q) rr[q] = rr[q] + p[i + q];
        }
        float s = ((rr[0] + rr[1]) + (rr[2] + rr[3]))
                + ((rr[4] + rr[5]) + (rr[6] + rr[7]));
        sq[b * 8192 + nt * 64 + j] = s;
    }
}

// ---- kNN filter via MFMA (r14-verified: warm-up 8 + ring + early-exit
// drain + rotating prefetch; 292us stable). ----
__global__ void __launch_bounds__(256) k_knn(const _Float16* __restrict__ fh,
                                             const float* __restrict__ sq,
                                             unsigned* __restrict__ part) {
    __shared__ unsigned ring[4][16 * 64];     // 16 KiB, slot-major, lane-private cols
    int lane = threadIdx.x & 63;
    int wv = threadIdx.x >> 6;
    int w = blockIdx.x * 4 + wv;              // 0..8191
    int g = w >> 2;                           // row group 0..2047
    int chunk = w & 3;                        // 0..3
    int n0 = g * 16;
    int b = n0 >> 13;
    int l16 = lane & 15, quad = lane >> 4;

    const _Float16* bp = fh + (size_t)(n0 + l16) * 64 + quad * 8;
    half8 bf0 = *(const half8*)bp;
    half8 bf1 = *(const half8*)(bp + 32);
#pragma unroll
    for (int j = 0; j < 8; ++j) { bf0[j] = bf0[j] * (_Float16)-2.0f; bf1[j] = bf1[j] * (_Float16)-2.0f; }
    float s512n = sq[n0 + l16] + 512.0f;

    unsigned lst[KCH];
#pragma unroll
    for (int i = 0; i < KCH; ++i) lst[i] = 0xFFFFFFFFu;
    unsigned* rg = ring[wv];

    int cb = chunk * CHSZ;
    const _Float16* ap = fh + (size_t)((b << 13) + cb + l16) * 64 + quad * 8;
    const float* sqp = sq + (b << 13) + cb + quad * 4;

    // warm-up: first 8 iterations (128 samples) insert all keys directly
#pragma unroll
    for (int s = 0; s < 8; ++s) {
        half8 af0 = *(const half8*)ap;
        half8 af1 = *(const half8*)(ap + 32);
        float4 sqv = *(const float4*)sqp;
        ap += 16 * 64;
        sqp += 16;
        float4v acc = {s512n + sqv.x, s512n + sqv.y, s512n + sqv.z, s512n + sqv.w};
        acc = __builtin_amdgcn_mfma_f32_16x16x32_f16(af0, bf0, acc, 0, 0, 0);
        acc = __builtin_amdgcn_mfma_f32_16x16x32_f16(af1, bf1, acc, 0, 0, 0);
        int mbase = s * 16 + quad * 4;
#pragma unroll
        for (int r = 0; r < 4; ++r) {
            unsigned key = (__float_as_uint(acc[r]) & 0xFFFFF800u) | (unsigned)(mbase + r);
            ins12(lst, key);
        }
    }
    unsigned thr = lst[KCH - 1];
    unsigned cnt = 0, drained = 0;

    // prologue load for s=8
    half8 af0 = *(const half8*)ap;
    half8 af1 = *(const half8*)(ap + 32);
    float4 sqv = *(const float4*)sqp;
    ap += 16 * 64;
    sqp += 16;

    for (int s = 8; s < CHSZ / 16; ++s) {
        half8 cf0 = af0;
        half8 cf1 = af1;
        float4 csq = sqv;
        // prefetch s+1 (one-past-end read is in-bounds workspace, unused)
        af0 = *(const half8*)ap;
        af1 = *(const half8*)(ap + 32);
        sqv = *(const float4*)sqp;
        ap += 16 * 64;
        sqp += 16;
        float4v acc = {s512n + csq.x, s512n + csq.y, s512n + csq.z, s512n + csq.w};
        acc = __builtin_amdgcn_mfma_f32_16x16x32_f16(cf0, bf0, acc, 0, 0, 0);
        acc = __builtin_amdgcn_mfma_f32_16x16x32_f16(cf1, bf1, acc, 0, 0, 0);
        int mbase = s * 16 + quad * 4;
#pragma unroll
        for (int r = 0; r < 4; ++r) {
            unsigned key = (__float_as_uint(acc[r]) & 0xFFFFF800u) | (unsigned)(mbase + r);
            rg[((cnt & 15u) << 6) + lane] = key;    // garbage if !qualify: never read
            cnt += (key < thr) ? 1u : 0u;
        }
        if (__any((cnt - drained) >= 13u)) {
#pragma unroll
            for (int dr = 0; dr < 16; ++dr) {
                if (!__any(drained + dr < cnt)) break;   // rounds past max-pending: ~free
                if (drained + dr < cnt) {
                    unsigned k2 = rg[(((drained + dr) & 15u) << 6) + lane];
                    ins12(lst, k2);
                }
            }
            drained = cnt;
            thr = lst[KCH - 1];
        }
    }
    // final drain: all lanes have pending <= 12 (else last in-loop flush fired)
#pragma unroll
    for (int dr = 0; dr < 12; ++dr) {
        if (!__any(drained + dr < cnt)) break;
        if (drained + dr < cnt) {
            unsigned k2 = rg[(((drained + dr) & 15u) << 6) + lane];
            ins12(lst, k2);
        }
    }
    unsigned* po = part + ((size_t)((n0 + l16) * 4 + chunk) * 4 + quad) * 6;
#pragma unroll
    for (int i = 0; i < 6; ++i)
        po[i] = (lst[2*i] & 0x7FFu) | ((lst[2*i+1] & 0x7FFu) << 16);
}

// ---- re-rank: 3 WAVES per row, ONE SURVIVOR PER THREAD. The r14 version
// ran 3 batches serially per wave (critical path ~5.6K cy); here the 3
// batches run CONCURRENTLY (one per wave): each wave cooperatively stages
// ITS 64 candidate rows (r10-verified half-tile global_load_lds flow, one
// batch each), chains, writes its key; one __syncthreads; 192-wide rank.
// mbuf/stage remain wave-private (own-wave lanes write the staged range ->
// lgkmcnt(0) suffices, k_conv-proven). LDS 26880B -> 6 blocks/CU = 4.5
// waves/SIMD (unchanged). fmaf order bit-exact; skey=(key<<8)|j distinct
// by construction; rank via strict < bijects onto 0..191 = lax.top_k.
__global__ void __launch_bounds__(192) k_refine(const float* __restrict__ f,
                                                const float* __restrict__ sq,
                                                const unsigned* __restrict__ part,
                                                int* __restrict__ idx) {
    __shared__ __align__(16) float rows[3][2048];              // 3 waves x 8 KiB
    __shared__ __align__(16) unsigned long long keybuf[192];
    __shared__ int mbuf[192];
    int lane = threadIdx.x & 63;
    int wv = threadIdx.x >> 6;                // 0..2
    int n = blockIdx.x;                       // 0..32767
    int b = n >> 13;
    float ctr[64];
    const float4* cf = (const float4*)(f + (size_t)n * 64);
#pragma unroll
    for (int i = 0; i < 16; ++i) {
        float4 v = cf[i];
        ctr[4*i] = v.x; ctr[4*i+1] = v.y; ctr[4*i+2] = v.z; ctr[4*i+3] = v.w;
    }
    float sqn = sq[n];
    const float* fb = f + ((size_t)(b << 13)) * 64;
    const float* sqb = sq + (b << 13);
    const unsigned* pl = part + (size_t)n * (NCHUNK * 4 * 6);
    int j = wv * 64 + lane;                   // survivor position 0..191
    int chunk = j / 48;
    int jj = j - chunk * 48;
    int subset = jj / 12, ii = jj - subset * 12;
    unsigned wrd = pl[(chunk * 4 + subset) * 6 + (ii >> 1)];
    int mm = chunk * CHSZ + (int)((ii & 1) ? (wrd >> 16) & 0x7FFu : wrd & 0x7FFu);
    mbuf[j] = mm;
    float sqm = sqb[mm];
    __builtin_amdgcn_s_waitcnt(0xc07f);      // lgkmcnt(0): own-wave mbuf visible
    __builtin_amdgcn_sched_barrier(0);
    float* rw = rows[wv];
    const int r8 = lane >> 3, c8 = lane & 7;
    float a = 0.f;
#pragma unroll
    for (int h = 0; h < 2; ++h) {
        // stage half h of THIS wave's 64 candidate rows: 8 x global_load_lds.
        // Instr t writes rows t*8..t*8+7 linearly; lane r8*8+c8 supplies row
        // R's slot c8 = global col-group c8^(R&7) (r10-verified swizzle).
#pragma unroll
        for (int t = 0; t < 8; ++t) {
            int R = t * 8 + r8;
            int mR = mbuf[wv * 64 + R];
            const float* src = fb + (size_t)mR * 64 + h * 32 + ((c8 ^ (R & 7)) << 2);
            __builtin_amdgcn_global_load_lds(
                (const __attribute__((address_space(1))) void*)src,
                (__attribute__((address_space(3))) void*)(rw + t * 256),
                16, 0, 0);
        }
        asm volatile("s_waitcnt vmcnt(0)" ::: "memory");
        __builtin_amdgcn_sched_barrier(0);
        {
#pragma clang fp contract(off)
#pragma unroll
            for (int c = 0; c < 8; ++c) {
                float4 v = *(const float4*)(rw + lane * 32 + ((c ^ (lane & 7)) << 2));
                int cc = h * 8 + c;
                a = fmaf(v.x, ctr[4*cc],   a);
                a = fmaf(v.y, ctr[4*cc+1], a);
                a = fmaf(v.z, ctr[4*cc+2], a);
                a = fmaf(v.w, ctr[4*cc+3], a);
            }
        }
        __builtin_amdgcn_sched_barrier(0);  // next half's DMA stays below reads
    }
    float d;
    {
#pragma clang fp contract(off)
        d = (sqn + (-2.0f * a)) + sqm;
    }
    unsigned long long key = (((unsigned long long)encf(d)) << 13) | (unsigned long long)mm;
    unsigned long long skey = (key << 8) | (unsigned long long)j;
    keybuf[j] = skey;
    __syncthreads();                          // all 192 keys visible block-wide
    unsigned r0 = 0;
#pragma unroll 8
    for (int t = 0; t < 192; t += 2) {
        unsigned long long ka = keybuf[t];
        unsigned long long kc = keybuf[t + 1];
        r0 += (ka < skey);
        r0 += (kc < skey);
    }
    if (r0 < K_) idx[(size_t)n * K_ + r0] = (int)((skey >> 8) & 0x1FFFull);
}

// ---- BN1 stats via MFMA: wave = 80 edge rows, h1 = f_m.W1d + f_n.Wcd ----
__global__ void __launch_bounds__(256) k_stats(const _Float16* __restrict__ fh,
                                               const int* __restrict__ idx,
                                               const _Float16* __restrict__ w1d_h,
                                               const _Float16* __restrict__ wcd_h,
                                               float* __restrict__ part1) {
    int lane = threadIdx.x & 63;
    int wv = threadIdx.x >> 6;
    int w = blockIdx.x * 4 + wv;              // 0..8191
    int l16 = lane & 15, quad = lane >> 4;
    half8 B1[4][2], Bc[4][2];
#pragma unroll
    for (int g = 0; g < 4; ++g) {
        const _Float16* p1 = w1d_h + (g * 16 + l16) * 64 + quad * 8;
        const _Float16* pc = wcd_h + (g * 16 + l16) * 64 + quad * 8;
        B1[g][0] = *(const half8*)p1;  B1[g][1] = *(const half8*)(p1 + 32);
        Bc[g][0] = *(const half8*)pc;  Bc[g][1] = *(const half8*)(pc + 32);
    }
    float accS[4] = {0.f, 0.f, 0.f, 0.f}, accQ[4] = {0.f, 0.f, 0.f, 0.f};
    int rbase = w * 80;
#pragma unroll
    for (int t = 0; t < 5; ++t) {
        int r = rbase + t * 16 + l16;
        unsigned n = (unsigned)r / 20u;
        int b = (int)(n >> 13);
        int mg = (b << 13) + idx[r];
        const _Float16* amp = fh + (size_t)mg * 64 + quad * 8;
        const _Float16* anp = fh + (size_t)n * 64 + quad * 8;
        half8 Am0 = *(const half8*)amp, Am1 = *(const half8*)(amp + 32);
        half8 An0 = *(const half8*)anp, An1 = *(const half8*)(anp + 32);
#pragma unroll
        for (int g = 0; g < 4; ++g) {
            float4v acc = {0.f, 0.f, 0.f, 0.f};
            acc = __builtin_amdgcn_mfma_f32_16x16x32_f16(Am0, B1[g][0], acc, 0, 0, 0);
            acc = __builtin_amdgcn_mfma_f32_16x16x32_f16(Am1, B1[g][1], acc, 0, 0, 0);
            acc = __builtin_amdgcn_mfma_f32_16x16x32_f16(An0, Bc[g][0], acc, 0, 0, 0);
            acc = __builtin_amdgcn_mfma_f32_16x16x32_f16(An1, Bc[g][1], acc, 0, 0, 0);
#pragma unroll
            for (int j = 0; j < 4; ++j) {
                float h = acc[j];
                accS[g] += h;
                accQ[g] = fmaf(h, h, accQ[g]);
            }
        }
    }
#pragma unroll
    for (int g = 0; g < 4; ++g) {
        accS[g] += __shfl_xor(accS[g], 16); accS[g] += __shfl_xor(accS[g], 32);
        accQ[g] += __shfl_xor(accQ[g], 16); accQ[g] += __shfl_xor(accQ[g], 32);
    }
    float oS = quad == 0 ? accS[0] : quad == 1 ? accS[1] : quad == 2 ? accS[2] : accS[3];
    float oQ = quad == 0 ? accQ[0] : quad == 1 ? accQ[1] : quad == 2 ? accQ[2] : accQ[3];
    part1[w * 128 + quad * 16 + l16] = oS;
    part1[w * 128 + 64 + quad * 16 + l16] = oQ;
}

// ---- finalize BN stats -> (a, c) affine. FUSED k_prep2 when W1 != nullptr ----
__global__ void k_fin(const float* __restrict__ part, int nw,
                      const float* __restrict__ g, const float* __restrict__ bt,
                      float2* __restrict__ ac,
                      const float* __restrict__ W1,
                      _Float16* __restrict__ w1s_h,
                      _Float16* __restrict__ wcds_h) {
    __shared__ double ls[256], lq[256];
    __shared__ float sa;
    int o = blockIdx.x;
    double s = 0.0, q = 0.0;
    for (int w = threadIdx.x; w < nw; w += 256) {
        s += (double)part[w * 128 + o];
        q += (double)part[w * 128 + 64 + o];
    }
    ls[threadIdx.x] = s; lq[threadIdx.x] = q;
    __syncthreads();
    for (int st = 128; st >= 1; st >>= 1) {
        if (threadIdx.x < st) {
            ls[threadIdx.x] += ls[threadIdx.x + st];
            lq[threadIdx.x] += lq[threadIdx.x + st];
        }
        __syncthreads();
    }
    if (threadIdx.x == 0) {
        double cnt = 655360.0;
        double mean = ls[0] / cnt;
        double var = lq[0] / cnt - mean * mean;
        float a = g[o] * (float)(1.0 / sqrt(var + 1e-5));
        ac[o] = make_float2(a, bt[o] - (float)mean * a);
        sa = a;
    }
    if (W1) {                                 // fused k_prep2
        __syncthreads();
        float a = sa;
        int t = threadIdx.x;
        if (t < 64) {
            w1s_h[o * 64 + t] = (_Float16)(a * W1[o * 128 + t]);
        } else if (t < 128) {
            int c = t - 64;
            wcds_h[o * 64 + c] = (_Float16)(a * (W1[o * 128 + 64 + c] - W1[o * 128 + c]));
        }
    }
}

// ---- fused conv1(+BN1+lrelu)+conv2 + BN2 stats + max/min, all via MFMA ----
// wave = 80 edge rows = exactly 4 n's. conv1: c1 in acc-init, a1 in weights.
// LDS 16x72 fp16 transpose (wave-private, DS in-order -> waitcnt only).
__global__ void __launch_bounds__(256) k_conv(const _Float16* __restrict__ fh,
                                              const int* __restrict__ idx,
                                              const _Float16* __restrict__ w1s,
                                              const _Float16* __restrict__ wcds,
                                              const _Float16* __restrict__ w2h,
                                              const float2* __restrict__ a1c1,
                                              float* __restrict__ hmax,
                                              __hip_bfloat16* __restrict__ hmin,
                                              float* __restrict__ part2) {
    __shared__ _Float16 gt[4][16 * 72];
    int lane = threadIdx.x & 63;
    int wv = threadIdx.x >> 6;
    int w = blockIdx.x * 4 + wv;              // 0..8191
    int l16 = lane & 15, quad = lane >> 4;
    half8 B1[4][2], Bc[4][2], B2[4][2];
    float c1v[4];
#pragma unroll
    for (int g = 0; g < 4; ++g) {
        const _Float16* p1 = w1s + (g * 16 + l16) * 64 + quad * 8;
        const _Float16* pc = wcds + (g * 16 + l16) * 64 + quad * 8;
        const _Float16* p2 = w2h + (g * 16 + l16) * 64 + quad * 8;
        B1[g][0] = *(const half8*)p1;  B1[g][1] = *(const half8*)(p1 + 32);
        Bc[g][0] = *(const half8*)pc;  Bc[g][1] = *(const half8*)(pc + 32);
        B2[g][0] = *(const half8*)p2;  B2[g][1] = *(const half8*)(p2 + 32);
        c1v[g] = a1c1[g * 16 + l16].y;
    }
    float accS[4] = {0.f, 0.f, 0.f, 0.f}, accQ[4] = {0.f, 0.f, 0.f, 0.f};
    float mx[4][4], mn[4][4];
#pragma unroll
    for (int a = 0; a < 4; ++a)
#pragma unroll
        for (int g = 0; g < 4; ++g) { mx[a][g] = -3.0e38f; mn[a][g] = 3.0e38f; }
    int rbase = w * 80;
    _Float16* gw = gt[wv];
#pragma unroll
    for (int t = 0; t < 5; ++t) {
        int r = rbase + t * 16 + l16;
        unsigned n = (unsigned)r / 20u;
        int b = (int)(n >> 13);
        int mg = (b << 13) + idx[r];
        const _Float16* amp = fh + (size_t)mg * 64 + quad * 8;
        const _Float16* anp = fh + (size_t)n * 64 + quad * 8;
        half8 Am0 = *(const half8*)amp, Am1 = *(const half8*)(amp + 32);
        half8 An0 = *(const half8*)anp, An1 = *(const half8*)(anp + 32);
#pragma unroll
        for (int g = 0; g < 4; ++g) {
            float4v acc = {c1v[g], c1v[g], c1v[g], c1v[g]};
            acc = __builtin_amdgcn_mfma_f32_16x16x32_f16(Am0, B1[g][0], acc, 0, 0, 0);
            acc = __builtin_amdgcn_mfma_f32_16x16x32_f16(Am1, B1[g][1], acc, 0, 0, 0);
            acc = __builtin_amdgcn_mfma_f32_16x16x32_f16(An0, Bc[g][0], acc, 0, 0, 0);
            acc = __builtin_amdgcn_mfma_f32_16x16x32_f16(An1, Bc[g][1], acc, 0, 0, 0);
#pragma unroll
            for (int j = 0; j < 4; ++j) {
                float v = acc[j];
                v = v >= 0.f ? v : 0.2f * v;
                gw[(quad * 4 + j) * 72 + g * 16 + l16] = (_Float16)v;
            }
        }
        __builtin_amdgcn_s_waitcnt(0xc07f);   // lgkmcnt(0): writes visible in-wave
        half8 A20 = *(const half8*)(gw + l16 * 72 + quad * 8);
        half8 A21 = *(const half8*)(gw + l16 * 72 + 32 + quad * 8);
#pragma unroll
        for (int g = 0; g < 4; ++g) {
            float4v acc = {0.f, 0.f, 0.f, 0.f};
            acc = __builtin_amdgcn_mfma_f32_16x16x32_f16(A20, B2[g][0], acc, 0, 0, 0);
            acc = __builtin_amdgcn_mfma_f32_16x16x32_f16(A21, B2[g][1], acc, 0, 0, 0);
#pragma unroll
            for (int j = 0; j < 4; ++j) {
                float h2 = acc[j];
                accS[g] += h2;
                accQ[g] = fmaf(h2, h2, accQ[g]);
                const int rowbase = t * 16 + j;          // + quad*4 at runtime
                const int nlo = rowbase / 20;
                const int nhi = (rowbase + 12) / 20;
                if (nlo == nhi) {
                    mx[nlo][g] = fmaxf(mx[nlo][g], h2);
                    mn[nlo][g] = fminf(mn[nlo][g], h2);
                } else {
                    bool hi = (quad * 4) >= (nhi * 20 - rowbase);
                    mx[nlo][g] = (!hi && h2 > mx[nlo][g]) ? h2 : mx[nlo][g];
                    mn[nlo][g] = (!hi && h2 < mn[nlo][g]) ? h2 : mn[nlo][g];
                    mx[nhi][g] = (hi && h2 > mx[nhi][g]) ? h2 : mx[nhi][g];
                    mn[nhi][g] = (hi && h2 < mn[nhi][g]) ? h2 : mn[nhi][g];
                }
            }
        }
    }
#pragma unroll
    for (int g = 0; g < 4; ++g) {
        accS[g] += __shfl_xor(accS[g], 16); accS[g] += __shfl_xor(accS[g], 32);
        accQ[g] += __shfl_xor(accQ[g], 16); accQ[g] += __shfl_xor(accQ[g], 32);
    }
#pragma unroll
    for (int a = 0; a < 4; ++a)
#pragma unroll
        for (int g = 0; g < 4; ++g) {
            mx[a][g] = fmaxf(mx[a][g], __shfl_xor(mx[a][g], 16));
            mx[a][g] = fmaxf(mx[a][g], __shfl_xor(mx[a][g], 32));
            mn[a][g] = fminf(mn[a][g], __shfl_xor(mn[a][g], 16));
            mn[a][g] = fminf(mn[a][g], __shfl_xor(mn[a][g], 32));
        }
    int nb = w * 4;
#pragma unroll
    for (int a = 0; a < 4; ++a) {
        float ox = quad == 0 ? mx[a][0] : quad == 1 ? mx[a][1] : quad == 2 ? mx[a][2] : mx[a][3];
        float on = quad == 0 ? mn[a][0] : quad == 1 ? mn[a][1] : quad == 2 ? mn[a][2] : mn[a][3];
        hmax[(size_t)(nb + a) * 64 + quad * 16 + l16] = ox;
        hmin[(size_t)(nb + a) * 64 + quad * 16 + l16] = __float2bfloat16(on);
    }
    float oS = quad == 0 ? accS[0] : quad == 1 ? accS[1] : quad == 2 ? accS[2] : accS[3];
    float oQ = quad == 0 ? accQ[0] : quad == 1 ? accQ[1] : quad == 2 ? accQ[2] : accQ[3];
    part2[w * 128 + quad * 16 + l16] = oS;
    part2[w * 128 + 64 + quad * 16 + l16] = oQ;
}

// ---- epilogue: BN2 affine + lrelu on max (min if a2<0), transpose out ----
__global__ void __launch_bounds__(256) k_out(const float* __restrict__ hmax,
                                             const __hip_bfloat16* __restrict__ hmin,
                                             const float2* __restrict__ a2c2,
                                             float* __restrict__ out) {
    __shared__ float tmx[64][65], tmn[64][65];
    int blk = blockIdx.x;
    int b = blk >> 7, nt = blk & 127;
    int r = threadIdx.x >> 6, j = threadIdx.x & 63;
    size_t nbase = (size_t)(b * 8192 + nt * 64);
#pragma unroll
    for (int i = 0; i < 16; ++i) {
        int nr = i * 4 + r;
        tmx[nr][j] = hmax[(nbase + nr) * 64 + j];
        tmn[nr][j] = __bfloat162float(hmin[(nbase + nr) * 64 + j]);
    }
    __syncthreads();
#pragma unroll
    for (int i = 0; i < 16; ++i) {
        int o = i * 4 + r;
        float2 ac = a2c2[o];
        float v = (ac.x >= 0.f) ? tmx[j][o] : tmn[j][o];
        float h = fmaf(v, ac.x, ac.y);
        h = h >= 0.f ? h : 0.2f * h;
        out[((size_t)(b * 64 + o)) * 8192 + nt * 64 + j] = h;
    }
}

extern "C" void kernel_launch(void* const* d_in, const int* in_sizes, int n_in,
                              void* d_out, int out_size, void* d_ws, size_t ws_size,
                              hipStream_t stream) {
    (void)in_sizes; (void)n_in; (void)out_size; (void)ws_size;
    const float* x  = (const float*)d_in[0];
    const float* W1 = (const float*)d_in[1];
    const float* g1 = (const float*)d_in[2];
    const float* b1 = (const float*)d_in[3];
    const float* W2 = (const float*)d_in[4];
    const float* g2 = (const float*)d_in[5];
    const float* b2 = (const float*)d_in[6];
    float* out = (float*)d_out;
    char* ws = (char*)d_ws;

    float*     f      = (float*)    (ws + 0);          // 8,388,608 (dead after refine)
    __hip_bfloat16* hmin = (__hip_bfloat16*)(ws + 0);  // 4,194,304 (aliases f)
    _Float16*  fh     = (_Float16*) (ws + 8388608);    // 4,194,304 (live thru conv)
    float*     sq     = (float*)    (ws + 12582912);   //   131,072
    int*       idx    = (int*)      (ws + 12713984);   // 2,621,440
    _Float16*  w1d_h  = (_Float16*) (ws + 15335424);   //     8,192
    _Float16*  wcd_h  = (_Float16*) (ws + 15343616);   //     8,192
    _Float16*  w2_h   = (_Float16*) (ws + 15351808);   //     8,192
    _Float16*  w1s_h  = (_Float16*) (ws + 15360000);   //     8,192
    _Float16*  wcds_h = (_Float16*) (ws + 15368192);   //     8,192
    float2*    a1c1   = (float2*)   (ws + 15376384);   //       512
    float2*    a2c2   = (float2*)   (ws + 15376896);   //       512
    char*      U      =              ws + 15377408;    // 12,582,912 union
    unsigned*  part_knn = (unsigned*)U;                // 12,582,912 (dead after refine)
    float*     part12 = (float*)    (U + 0);           //  4,194,304
    float*     hmax   = (float*)    (U + 4194304);     //  8,388,608
    // total ws: 27,960,320 bytes (< r9's proven 37.88 MB)

    k_transpose<<<528, 256, 0, stream>>>(x, f, fh, sq, W1, W2, w1d_h, wcd_h, w2_h);
    k_knn<<<2048, 256, 0, stream>>>(fh, sq, part_knn);
    k_refine<<<32768, 192, 0, stream>>>(f, sq, part_knn, idx);
    k_stats<<<2048, 256, 0, stream>>>(fh, idx, w1d_h, wcd_h, part12);
    k_fin<<<64, 256, 0, stream>>>(part12, 8192, g1, b1, a1c1, W1, w1s_h, wcds_h);
    k_conv<<<2048, 256, 0, stream>>>(fh, idx, w1s_h, wcds_h, w2_h, a1c1, hmax, hmin, part12);
    k_fin<<<64, 256, 0, stream>>>(part12, 8192, g2, b2, a2c2, nullptr, nullptr, nullptr);
    k_out<<<512, 256, 0, stream>>>(hmax, hmin, a2c2, out);
}

// Round 17
// 586.727 us; speedup vs baseline: 1.0227x; 1.0227x over previous
//
#include <hip/hip_runtime.h>
#include <hip/hip_bf16.h>
#include <stdint.h>

typedef _Float16 half8 __attribute__((ext_vector_type(8)));
typedef float float4v __attribute__((ext_vector_type(4)));

#define K_ 20
#define KCH 12
#define NCHUNK 4
#define CHSZ 2048
#define NTOT 32768        // B*N rows
#define ROWS 655360       // NTOT*K_

__device__ __forceinline__ unsigned encf(float v) {
    unsigned u = __float_as_uint(v);
    return ((int)u < 0) ? ~u : (u | 0x80000000u);
}

// 12-deep sorted-insert (ascending keys), fully register-resident
__device__ __forceinline__ void ins12(unsigned* lst, unsigned key) {
    bool chi = key < lst[11];
#pragma unroll
    for (int j = 11; j >= 1; --j) {
        bool clo = key < lst[j - 1];
        lst[j] = clo ? lst[j - 1] : (chi ? key : lst[j]);
        chi = clo;
    }
    lst[0] = chi ? key : lst[0];
}

// ---- transpose x (B,C,N) -> f fp32 + fh fp16 + numpy-bit-exact sq ----
// sq: numpy pairwise_sum scalar 8-accumulator branch (r4-verified, DO NOT TOUCH)
// FUSED: blocks >= 512 run the old k_prep (fp16 weight tiles).
__global__ void __launch_bounds__(256) k_transpose(const float* __restrict__ x,
                                                   float* __restrict__ f,
                                                   _Float16* __restrict__ fh,
                                                   float* __restrict__ sq,
                                                   const float* __restrict__ W1,
                                                   const float* __restrict__ W2,
                                                   _Float16* __restrict__ w1d_h,
                                                   _Float16* __restrict__ wcd_h,
                                                   _Float16* __restrict__ w2_h) {
    __shared__ float tile[64][65];
    int blk = blockIdx.x;              // 0..527
    if (blk >= 512) {                  // fused k_prep: 16 blocks
        int i = (blk - 512) * 256 + threadIdx.x;   // 0..4095
        int o = i >> 6, c = i & 63;
        w1d_h[i] = (_Float16)W1[o * 128 + c];
        wcd_h[i] = (_Float16)(W1[o * 128 + 64 + c] - W1[o * 128 + c]);
        w2_h[i]  = (_Float16)W2[i];
        return;
    }
    int b = blk >> 7, nt = blk & 127;
    int r = threadIdx.x >> 6, j = threadIdx.x & 63;
    const float* xb = x + ((size_t)b * 64) * 8192 + nt * 64;
#pragma unroll
    for (int i = 0; i < 16; ++i) {
        int c = i * 4 + r;
        tile[c][j] = xb[(size_t)c * 8192 + j];
    }
    __syncthreads();
    size_t nbase = (size_t)(b * 8192 + nt * 64);
    float* fb = f + nbase * 64;
    _Float16* fhb = fh + nbase * 64;
#pragma unroll
    for (int i = 0; i < 16; ++i) {
        int n = i * 4 + r;
        float v = tile[j][n];
        fb[(size_t)n * 64 + j] = v;
        fhb[(size_t)n * 64 + j] = (_Float16)v;
    }
    if (r == 0) {
#pragma clang fp contract(off)
        float p[64];
#pragma unroll
        for (int c = 0; c < 64; ++c) { float v = tile[c][j]; p[c] = v * v; }
        float rr[8];
#pragma unroll
        for (int q = 0; q < 8; ++q) rr[q] = p[q];
#pragma unroll
        for (int i = 8; i < 64; i += 8) {
#pragma unroll
            for (int q = 0; q < 8; ++q) rr[q] = rr[q] + p[i + q];
        }
        float s = ((rr[0] + rr[1]) + (rr[2] + rr[3]))
                + ((rr[4] + rr[5]) + (rr[6] + rr[7]));
        sq[b * 8192 + nt * 64 + j] = s;
    }
}

// ---- kNN filter via MFMA (r14-verified: warm-up 8 + ring + early-exit
// drain + rotating prefetch; 292us stable). ----
__global__ void __launch_bounds__(256) k_knn(const _Float16* __restrict__ fh,
                                             const float* __restrict__ sq,
                                             unsigned* __restrict__ part) {
    __shared__ unsigned ring[4][16 * 64];     // 16 KiB, slot-major, lane-private cols
    int lane = threadIdx.x & 63;
    int wv = threadIdx.x >> 6;
    int w = blockIdx.x * 4 + wv;              // 0..8191
    int g = w >> 2;                           // row group 0..2047
    int chunk = w & 3;                        // 0..3
    int n0 = g * 16;
    int b = n0 >> 13;
    int l16 = lane & 15, quad = lane >> 4;

    const _Float16* bp = fh + (size_t)(n0 + l16) * 64 + quad * 8;
    half8 bf0 = *(const half8*)bp;
    half8 bf1 = *(const half8*)(bp + 32);
#pragma unroll
    for (int j = 0; j < 8; ++j) { bf0[j] = bf0[j] * (_Float16)-2.0f; bf1[j] = bf1[j] * (_Float16)-2.0f; }
    float s512n = sq[n0 + l16] + 512.0f;

    unsigned lst[KCH];
#pragma unroll
    for (int i = 0; i < KCH; ++i) lst[i] = 0xFFFFFFFFu;
    unsigned* rg = ring[wv];

    int cb = chunk * CHSZ;
    const _Float16* ap = fh + (size_t)((b << 13) + cb + l16) * 64 + quad * 8;
    const float* sqp = sq + (b << 13) + cb + quad * 4;

    // warm-up: first 8 iterations (128 samples) insert all keys directly
#pragma unroll
    for (int s = 0; s < 8; ++s) {
        half8 af0 = *(const half8*)ap;
        half8 af1 = *(const half8*)(ap + 32);
        float4 sqv = *(const float4*)sqp;
        ap += 16 * 64;
        sqp += 16;
        float4v acc = {s512n + sqv.x, s512n + sqv.y, s512n + sqv.z, s512n + sqv.w};
        acc = __builtin_amdgcn_mfma_f32_16x16x32_f16(af0, bf0, acc, 0, 0, 0);
        acc = __builtin_amdgcn_mfma_f32_16x16x32_f16(af1, bf1, acc, 0, 0, 0);
        int mbase = s * 16 + quad * 4;
#pragma unroll
        for (int r = 0; r < 4; ++r) {
            unsigned key = (__float_as_uint(acc[r]) & 0xFFFFF800u) | (unsigned)(mbase + r);
            ins12(lst, key);
        }
    }
    unsigned thr = lst[KCH - 1];
    unsigned cnt = 0, drained = 0;

    // prologue load for s=8
    half8 af0 = *(const half8*)ap;
    half8 af1 = *(const half8*)(ap + 32);
    float4 sqv = *(const float4*)sqp;
    ap += 16 * 64;
    sqp += 16;

    for (int s = 8; s < CHSZ / 16; ++s) {
        half8 cf0 = af0;
        half8 cf1 = af1;
        float4 csq = sqv;
        // prefetch s+1 (one-past-end read is in-bounds workspace, unused)
        af0 = *(const half8*)ap;
        af1 = *(const half8*)(ap + 32);
        sqv = *(const float4*)sqp;
        ap += 16 * 64;
        sqp += 16;
        float4v acc = {s512n + csq.x, s512n + csq.y, s512n + csq.z, s512n + csq.w};
        acc = __builtin_amdgcn_mfma_f32_16x16x32_f16(cf0, bf0, acc, 0, 0, 0);
        acc = __builtin_amdgcn_mfma_f32_16x16x32_f16(cf1, bf1, acc, 0, 0, 0);
        int mbase = s * 16 + quad * 4;
#pragma unroll
        for (int r = 0; r < 4; ++r) {
            unsigned key = (__float_as_uint(acc[r]) & 0xFFFFF800u) | (unsigned)(mbase + r);
            rg[((cnt & 15u) << 6) + lane] = key;    // garbage if !qualify: never read
            cnt += (key < thr) ? 1u : 0u;
        }
        if (__any((cnt - drained) >= 13u)) {
#pragma unroll
            for (int dr = 0; dr < 16; ++dr) {
                if (!__any(drained + dr < cnt)) break;   // rounds past max-pending: ~free
                if (drained + dr < cnt) {
                    unsigned k2 = rg[(((drained + dr) & 15u) << 6) + lane];
                    ins12(lst, k2);
                }
            }
            drained = cnt;
            thr = lst[KCH - 1];
        }
    }
    // final drain: all lanes have pending <= 12 (else last in-loop flush fired)
#pragma unroll
    for (int dr = 0; dr < 12; ++dr) {
        if (!__any(drained + dr < cnt)) break;
        if (drained + dr < cnt) {
            unsigned k2 = rg[(((drained + dr) & 15u) << 6) + lane];
            ins12(lst, k2);
        }
    }
    unsigned* po = part + ((size_t)((n0 + l16) * 4 + chunk) * 4 + quad) * 6;
#pragma unroll
    for (int i = 0; i < 6; ++i)
        po[i] = (lst[2*i] & 0x7FFu) | ((lst[2*i+1] & 0x7FFu) << 16);
}

// ---- re-rank: one WAVE per row, HALF-TILE async staging (r10-verified,
// 4.5 waves/SIMD via keybuf-aliases-rows, r13/r14-verified passing at
// ~134us). rows is dead after the last chain read; same-wave DS in-order +
// explicit compiler memory barriers around the aliased u64 stores forbid
// TBAA reordering across the type-pun. LDS/block 17920 -> 9 blocks/CU.
// Ranking: skey=(key<<8)|position distinct by construction; rank via
// strict < bijects onto 0..191; matches lax.top_k.
__global__ void __launch_bounds__(128) k_refine(const float* __restrict__ f,
                                                const float* __restrict__ sq,
                                                const unsigned* __restrict__ part,
                                                int* __restrict__ idx) {
    __shared__ __align__(16) float rows[2][2048];              // 2 waves x 8 KiB
    __shared__ int mbuf[2][192];
    int lane = threadIdx.x & 63;
    int wv = threadIdx.x >> 6;                // 0..1
    int n = blockIdx.x * 2 + wv;              // 0..32767 (grid 16384)
    int b = n >> 13;
    float ctr[64];
    const float4* cf = (const float4*)(f + (size_t)n * 64);
#pragma unroll
    for (int i = 0; i < 16; ++i) {
        float4 v = cf[i];
        ctr[4*i] = v.x; ctr[4*i+1] = v.y; ctr[4*i+2] = v.z; ctr[4*i+3] = v.w;
    }
    float sqn = sq[n];
    const float* fb = f + ((size_t)(b << 13)) * 64;
    const float* sqb = sq + (b << 13);
    const unsigned* pl = part + (size_t)n * (NCHUNK * 4 * 6);
    int mm[3];
#pragma unroll
    for (int q = 0; q < 3; ++q) {
        int j = lane + q * 64;                // survivor position 0..191
        int chunk = j / 48;
        int jj = j - chunk * 48;
        int subset = jj / 12, i = jj - subset * 12;
        unsigned wrd = pl[(chunk * 4 + subset) * 6 + (i >> 1)];
        mm[q] = chunk * CHSZ + (int)((i & 1) ? (wrd >> 16) & 0x7FFu : wrd & 0x7FFu);
        mbuf[wv][j] = mm[q];
    }
    float sqmv[3];
#pragma unroll
    for (int q = 0; q < 3; ++q) sqmv[q] = sqb[mm[q]];
    __builtin_amdgcn_s_waitcnt(0xc07f);      // lgkmcnt(0): mbuf visible in-wave
    __builtin_amdgcn_sched_barrier(0);
    float* rw = rows[wv];
    const int r8 = lane >> 3, c8 = lane & 7;
    unsigned long long keys[3];
#pragma unroll
    for (int q = 0; q < 3; ++q) {
        float a = 0.f;                        // chain accumulator spans both halves
#pragma unroll
        for (int h = 0; h < 2; ++h) {
            // stage half h: 8 x global_load_lds (1KB each). Instr t writes
            // rows t*8..t*8+7 linearly; lane = r8*8+c8 supplies row R's slot
            // c8, whose content must be global col-group c8^(R&7).
#pragma unroll
            for (int t = 0; t < 8; ++t) {
                int R = t * 8 + r8;
                int mR = mbuf[wv][q * 64 + R];
                const float* src = fb + (size_t)mR * 64 + h * 32 + ((c8 ^ (R & 7)) << 2);
                __builtin_amdgcn_global_load_lds(
                    (const __attribute__((address_space(1))) void*)src,
                    (__attribute__((address_space(3))) void*)(rw + t * 256),
                    16, 0, 0);
            }
            asm volatile("s_waitcnt vmcnt(0)" ::: "memory");
            __builtin_amdgcn_sched_barrier(0);
            {
#pragma clang fp contract(off)
#pragma unroll
                for (int c = 0; c < 8; ++c) {
                    float4 v = *(const float4*)(rw + lane * 32 + ((c ^ (lane & 7)) << 2));
                    int cc = h * 8 + c;
                    a = fmaf(v.x, ctr[4*cc],   a);
                    a = fmaf(v.y, ctr[4*cc+1], a);
                    a = fmaf(v.z, ctr[4*cc+2], a);
                    a = fmaf(v.w, ctr[4*cc+3], a);
                }
            }
            __builtin_amdgcn_sched_barrier(0);  // next half's DMA stays below reads
        }
        float d;
        {
#pragma clang fp contract(off)
            d = (sqn + (-2.0f * a)) + sqmv[q];
        }
        unsigned long long key = (((unsigned long long)encf(d)) << 13) | (unsigned long long)mm[q];
        keys[q] = (key << 8) | (unsigned long long)(lane + q * 64);
    }
    // keybuf aliases rows (rows dead). Compiler memory barrier: forbid any
    // IR-level reordering of the u64 stores vs the float4 loads (type-pun).
    asm volatile("" ::: "memory");
    unsigned long long* kb = (unsigned long long*)rw;
    kb[lane]       = keys[0];
    kb[lane + 64]  = keys[1];
    kb[lane + 128] = keys[2];
    __builtin_amdgcn_s_waitcnt(0xc07f);      // lgkmcnt(0): keybuf visible
    asm volatile("" ::: "memory");
    __builtin_amdgcn_sched_barrier(0);
    unsigned r0 = 0, r1 = 0, r2 = 0;
#pragma unroll 8
    for (int j = 0; j < 192; j += 2) {
        unsigned long long ka = kb[j];
        unsigned long long kc = kb[j + 1];
        r0 += (ka < keys[0]); r0 += (kc < keys[0]);
        r1 += (ka < keys[1]); r1 += (kc < keys[1]);
        r2 += (ka < keys[2]); r2 += (kc < keys[2]);
    }
    int* io = idx + (size_t)n * K_;
    if (r0 < K_) io[r0] = (int)((keys[0] >> 8) & 0x1FFFull);
    if (r1 < K_) io[r1] = (int)((keys[1] >> 8) & 0x1FFFull);
    if (r2 < K_) io[r2] = (int)((keys[2] >> 8) & 0x1FFFull);
}

// ---- BN1 stats via MFMA: wave = 80 edge rows, h1 = f_m.W1d + f_n.Wcd ----
__global__ void __launch_bounds__(256) k_stats(const _Float16* __restrict__ fh,
                                               const int* __restrict__ idx,
                                               const _Float16* __restrict__ w1d_h,
                                               const _Float16* __restrict__ wcd_h,
                                               float* __restrict__ part1) {
    int lane = threadIdx.x & 63;
    int wv = threadIdx.x >> 6;
    int w = blockIdx.x * 4 + wv;              // 0..8191
    int l16 = lane & 15, quad = lane >> 4;
    half8 B1[4][2], Bc[4][2];
#pragma unroll
    for (int g = 0; g < 4; ++g) {
        const _Float16* p1 = w1d_h + (g * 16 + l16) * 64 + quad * 8;
        const _Float16* pc = wcd_h + (g * 16 + l16) * 64 + quad * 8;
        B1[g][0] = *(const half8*)p1;  B1[g][1] = *(const half8*)(p1 + 32);
        Bc[g][0] = *(const half8*)pc;  Bc[g][1] = *(const half8*)(pc + 32);
    }
    float accS[4] = {0.f, 0.f, 0.f, 0.f}, accQ[4] = {0.f, 0.f, 0.f, 0.f};
    int rbase = w * 80;
#pragma unroll
    for (int t = 0; t < 5; ++t) {
        int r = rbase + t * 16 + l16;
        unsigned n = (unsigned)r / 20u;
        int b = (int)(n >> 13);
        int mg = (b << 13) + idx[r];
        const _Float16* amp = fh + (size_t)mg * 64 + quad * 8;
        const _Float16* anp = fh + (size_t)n * 64 + quad * 8;
        half8 Am0 = *(const half8*)amp, Am1 = *(const half8*)(amp + 32);
        half8 An0 = *(const half8*)anp, An1 = *(const half8*)(anp + 32);
#pragma unroll
        for (int g = 0; g < 4; ++g) {
            float4v acc = {0.f, 0.f, 0.f, 0.f};
            acc = __builtin_amdgcn_mfma_f32_16x16x32_f16(Am0, B1[g][0], acc, 0, 0, 0);
            acc = __builtin_amdgcn_mfma_f32_16x16x32_f16(Am1, B1[g][1], acc, 0, 0, 0);
            acc = __builtin_amdgcn_mfma_f32_16x16x32_f16(An0, Bc[g][0], acc, 0, 0, 0);
            acc = __builtin_amdgcn_mfma_f32_16x16x32_f16(An1, Bc[g][1], acc, 0, 0, 0);
#pragma unroll
            for (int j = 0; j < 4; ++j) {
                float h = acc[j];
                accS[g] += h;
                accQ[g] = fmaf(h, h, accQ[g]);
            }
        }
    }
#pragma unroll
    for (int g = 0; g < 4; ++g) {
        accS[g] += __shfl_xor(accS[g], 16); accS[g] += __shfl_xor(accS[g], 32);
        accQ[g] += __shfl_xor(accQ[g], 16); accQ[g] += __shfl_xor(accQ[g], 32);
    }
    float oS = quad == 0 ? accS[0] : quad == 1 ? accS[1] : quad == 2 ? accS[2] : accS[3];
    float oQ = quad == 0 ? accQ[0] : quad == 1 ? accQ[1] : quad == 2 ? accQ[2] : accQ[3];
    part1[w * 128 + quad * 16 + l16] = oS;
    part1[w * 128 + 64 + quad * 16 + l16] = oQ;
}

// ---- finalize BN stats -> (a, c) affine. FUSED k_prep2 when W1 != nullptr ----
__global__ void k_fin(const float* __restrict__ part, int nw,
                      const float* __restrict__ g, const float* __restrict__ bt,
                      float2* __restrict__ ac,
                      const float* __restrict__ W1,
                      _Float16* __restrict__ w1s_h,
                      _Float16* __restrict__ wcds_h) {
    __shared__ double ls[256], lq[256];
    __shared__ float sa;
    int o = blockIdx.x;
    double s = 0.0, q = 0.0;
    for (int w = threadIdx.x; w < nw; w += 256) {
        s += (double)part[w * 128 + o];
        q += (double)part[w * 128 + 64 + o];
    }
    ls[threadIdx.x] = s; lq[threadIdx.x] = q;
    __syncthreads();
    for (int st = 128; st >= 1; st >>= 1) {
        if (threadIdx.x < st) {
            ls[threadIdx.x] += ls[threadIdx.x + st];
            lq[threadIdx.x] += lq[threadIdx.x + st];
        }
        __syncthreads();
    }
    if (threadIdx.x == 0) {
        double cnt = 655360.0;
        double mean = ls[0] / cnt;
        double var = lq[0] / cnt - mean * mean;
        float a = g[o] * (float)(1.0 / sqrt(var + 1e-5));
        ac[o] = make_float2(a, bt[o] - (float)mean * a);
        sa = a;
    }
    if (W1) {                                 // fused k_prep2
        __syncthreads();
        float a = sa;
        int t = threadIdx.x;
        if (t < 64) {
            w1s_h[o * 64 + t] = (_Float16)(a * W1[o * 128 + t]);
        } else if (t < 128) {
            int c = t - 64;
            wcds_h[o * 64 + c] = (_Float16)(a * (W1[o * 128 + 64 + c] - W1[o * 128 + c]));
        }
    }
}

// ---- fused conv1(+BN1+lrelu)+conv2 + BN2 stats + max/min, all via MFMA ----
// wave = 80 edge rows = exactly 4 n's. conv1: c1 in acc-init, a1 in weights.
// LDS 16x72 fp16 transpose (wave-private, DS in-order -> waitcnt only).
__global__ void __launch_bounds__(256) k_conv(const _Float16* __restrict__ fh,
                                              const int* __restrict__ idx,
                                              const _Float16* __restrict__ w1s,
                                              const _Float16* __restrict__ wcds,
                                              const _Float16* __restrict__ w2h,
                                              const float2* __restrict__ a1c1,
                                              float* __restrict__ hmax,
                                              __hip_bfloat16* __restrict__ hmin,
                                              float* __restrict__ part2) {
    __shared__ _Float16 gt[4][16 * 72];
    int lane = threadIdx.x & 63;
    int wv = threadIdx.x >> 6;
    int w = blockIdx.x * 4 + wv;              // 0..8191
    int l16 = lane & 15, quad = lane >> 4;
    half8 B1[4][2], Bc[4][2], B2[4][2];
    float c1v[4];
#pragma unroll
    for (int g = 0; g < 4; ++g) {
        const _Float16* p1 = w1s + (g * 16 + l16) * 64 + quad * 8;
        const _Float16* pc = wcds + (g * 16 + l16) * 64 + quad * 8;
        const _Float16* p2 = w2h + (g * 16 + l16) * 64 + quad * 8;
        B1[g][0] = *(const half8*)p1;  B1[g][1] = *(const half8*)(p1 + 32);
        Bc[g][0] = *(const half8*)pc;  Bc[g][1] = *(const half8*)(pc + 32);
        B2[g][0] = *(const half8*)p2;  B2[g][1] = *(const half8*)(p2 + 32);
        c1v[g] = a1c1[g * 16 + l16].y;
    }
    float accS[4] = {0.f, 0.f, 0.f, 0.f}, accQ[4] = {0.f, 0.f, 0.f, 0.f};
    float mx[4][4], mn[4][4];
#pragma unroll
    for (int a = 0; a < 4; ++a)
#pragma unroll
        for (int g = 0; g < 4; ++g) { mx[a][g] = -3.0e38f; mn[a][g] = 3.0e38f; }
    int rbase = w * 80;
    _Float16* gw = gt[wv];
#pragma unroll
    for (int t = 0; t < 5; ++t) {
        int r = rbase + t * 16 + l16;
        unsigned n = (unsigned)r / 20u;
        int b = (int)(n >> 13);
        int mg = (b << 13) + idx[r];
        const _Float16* amp = fh + (size_t)mg * 64 + quad * 8;
        const _Float16* anp = fh + (size_t)n * 64 + quad * 8;
        half8 Am0 = *(const half8*)amp, Am1 = *(const half8*)(amp + 32);
        half8 An0 = *(const half8*)anp, An1 = *(const half8*)(anp + 32);
#pragma unroll
        for (int g = 0; g < 4; ++g) {
            float4v acc = {c1v[g], c1v[g], c1v[g], c1v[g]};
            acc = __builtin_amdgcn_mfma_f32_16x16x32_f16(Am0, B1[g][0], acc, 0, 0, 0);
            acc = __builtin_amdgcn_mfma_f32_16x16x32_f16(Am1, B1[g][1], acc, 0, 0, 0);
            acc = __builtin_amdgcn_mfma_f32_16x16x32_f16(An0, Bc[g][0], acc, 0, 0, 0);
            acc = __builtin_amdgcn_mfma_f32_16x16x32_f16(An1, Bc[g][1], acc, 0, 0, 0);
#pragma unroll
            for (int j = 0; j < 4; ++j) {
                float v = acc[j];
                v = v >= 0.f ? v : 0.2f * v;
                gw[(quad * 4 + j) * 72 + g * 16 + l16] = (_Float16)v;
            }
        }
        __builtin_amdgcn_s_waitcnt(0xc07f);   // lgkmcnt(0): writes visible in-wave
        half8 A20 = *(const half8*)(gw + l16 * 72 + quad * 8);
        half8 A21 = *(const half8*)(gw + l16 * 72 + 32 + quad * 8);
#pragma unroll
        for (int g = 0; g < 4; ++g) {
            float4v acc = {0.f, 0.f, 0.f, 0.f};
            acc = __builtin_amdgcn_mfma_f32_16x16x32_f16(A20, B2[g][0], acc, 0, 0, 0);
            acc = __builtin_amdgcn_mfma_f32_16x16x32_f16(A21, B2[g][1], acc, 0, 0, 0);
#pragma unroll
            for (int j = 0; j < 4; ++j) {
                float h2 = acc[j];
                accS[g] += h2;
                accQ[g] = fmaf(h2, h2, accQ[g]);
                const int rowbase = t * 16 + j;          // + quad*4 at runtime
                const int nlo = rowbase / 20;
                const int nhi = (rowbase + 12) / 20;
                if (nlo == nhi) {
                    mx[nlo][g] = fmaxf(mx[nlo][g], h2);
                    mn[nlo][g] = fminf(mn[nlo][g], h2);
                } else {
                    bool hi = (quad * 4) >= (nhi * 20 - rowbase);
                    mx[nlo][g] = (!hi && h2 > mx[nlo][g]) ? h2 : mx[nlo][g];
                    mn[nlo][g] = (!hi && h2 < mn[nlo][g]) ? h2 : mn[nlo][g];
                    mx[nhi][g] = (hi && h2 > mx[nhi][g]) ? h2 : mx[nhi][g];
                    mn[nhi][g] = (hi && h2 < mn[nhi][g]) ? h2 : mn[nhi][g];
                }
            }
        }
    }
#pragma unroll
    for (int g = 0; g < 4; ++g) {
        accS[g] += __shfl_xor(accS[g], 16); accS[g] += __shfl_xor(accS[g], 32);
        accQ[g] += __shfl_xor(accQ[g], 16); accQ[g] += __shfl_xor(accQ[g], 32);
    }
#pragma unroll
    for (int a = 0; a < 4; ++a)
#pragma unroll
        for (int g = 0; g < 4; ++g) {
            mx[a][g] = fmaxf(mx[a][g], __shfl_xor(mx[a][g], 16));
            mx[a][g] = fmaxf(mx[a][g], __shfl_xor(mx[a][g], 32));
            mn[a][g] = fminf(mn[a][g], __shfl_xor(mn[a][g], 16));
            mn[a][g] = fminf(mn[a][g], __shfl_xor(mn[a][g], 32));
        }
    int nb = w * 4;
#pragma unroll
    for (int a = 0; a < 4; ++a) {
        float ox = quad == 0 ? mx[a][0] : quad == 1 ? mx[a][1] : quad == 2 ? mx[a][2] : mx[a][3];
        float on = quad == 0 ? mn[a][0] : quad == 1 ? mn[a][1] : quad == 2 ? mn[a][2] : mn[a][3];
        hmax[(size_t)(nb + a) * 64 + quad * 16 + l16] = ox;
        hmin[(size_t)(nb + a) * 64 + quad * 16 + l16] = __float2bfloat16(on);
    }
    float oS = quad == 0 ? accS[0] : quad == 1 ? accS[1] : quad == 2 ? accS[2] : accS[3];
    float oQ = quad == 0 ? accQ[0] : quad == 1 ? accQ[1] : quad == 2 ? accQ[2] : accQ[3];
    part2[w * 128 + quad * 16 + l16] = oS;
    part2[w * 128 + 64 + quad * 16 + l16] = oQ;
}

// ---- epilogue: BN2 affine + lrelu on max (min if a2<0), transpose out ----
__global__ void __launch_bounds__(256) k_out(const float* __restrict__ hmax,
                                             const __hip_bfloat16* __restrict__ hmin,
                                             const float2* __restrict__ a2c2,
                                             float* __restrict__ out) {
    __shared__ float tmx[64][65], tmn[64][65];
    int blk = blockIdx.x;
    int b = blk >> 7, nt = blk & 127;
    int r = threadIdx.x >> 6, j = threadIdx.x & 63;
    size_t nbase = (size_t)(b * 8192 + nt * 64);
#pragma unroll
    for (int i = 0; i < 16; ++i) {
        int nr = i * 4 + r;
        tmx[nr][j] = hmax[(nbase + nr) * 64 + j];
        tmn[nr][j] = __bfloat162float(hmin[(nbase + nr) * 64 + j]);
    }
    __syncthreads();
#pragma unroll
    for (int i = 0; i < 16; ++i) {
        int o = i * 4 + r;
        float2 ac = a2c2[o];
        float v = (ac.x >= 0.f) ? tmx[j][o] : tmn[j][o];
        float h = fmaf(v, ac.x, ac.y);
        h = h >= 0.f ? h : 0.2f * h;
        out[((size_t)(b * 64 + o)) * 8192 + nt * 64 + j] = h;
    }
}

extern "C" void kernel_launch(void* const* d_in, const int* in_sizes, int n_in,
                              void* d_out, int out_size, void* d_ws, size_t ws_size,
                              hipStream_t stream) {
    (void)in_sizes; (void)n_in; (void)out_size; (void)ws_size;
    const float* x  = (const float*)d_in[0];
    const float* W1 = (const float*)d_in[1];
    const float* g1 = (const float*)d_in[2];
    const float* b1 = (const float*)d_in[3];
    const float* W2 = (const float*)d_in[4];
    const float* g2 = (const float*)d_in[5];
    const float* b2 = (const float*)d_in[6];
    float* out = (float*)d_out;
    char* ws = (char*)d_ws;

    float*     f      = (float*)    (ws + 0);          // 8,388,608 (dead after refine)
    __hip_bfloat16* hmin = (__hip_bfloat16*)(ws + 0);  // 4,194,304 (aliases f)
    _Float16*  fh     = (_Float16*) (ws + 8388608);    // 4,194,304 (live thru conv)
    float*     sq     = (float*)    (ws + 12582912);   //   131,072
    int*       idx    = (int*)      (ws + 12713984);   // 2,621,440
    _Float16*  w1d_h  = (_Float16*) (ws + 15335424);   //     8,192
    _Float16*  wcd_h  = (_Float16*) (ws + 15343616);   //     8,192
    _Float16*  w2_h   = (_Float16*) (ws + 15351808);   //     8,192
    _Float16*  w1s_h  = (_Float16*) (ws + 15360000);   //     8,192
    _Float16*  wcds_h = (_Float16*) (ws + 15368192);   //     8,192
    float2*    a1c1   = (float2*)   (ws + 15376384);   //       512
    float2*    a2c2   = (float2*)   (ws + 15376896);   //       512
    char*      U      =              ws + 15377408;    // 12,582,912 union
    unsigned*  part_knn = (unsigned*)U;                // 12,582,912 (dead after refine)
    float*     part12 = (float*)    (U + 0);           //  4,194,304
    float*     hmax   = (float*)    (U + 4194304);     //  8,388,608
    // total ws: 27,960,320 bytes (< r9's proven 37.88 MB)

    k_transpose<<<528, 256, 0, stream>>>(x, f, fh, sq, W1, W2, w1d_h, wcd_h, w2_h);
    k_knn<<<2048, 256, 0, stream>>>(fh, sq, part_knn);
    k_refine<<<16384, 128, 0, stream>>>(f, sq, part_knn, idx);
    k_stats<<<2048, 256, 0, stream>>>(fh, idx, w1d_h, wcd_h, part12);
    k_fin<<<64, 256, 0, stream>>>(part12, 8192, g1, b1, a1c1, W1, w1s_h, wcds_h);
    k_conv<<<2048, 256, 0, stream>>>(fh, idx, w1s_h, wcds_h, w2_h, a1c1, hmax, hmin, part12);
    k_fin<<<64, 256, 0, stream>>>(part12, 8192, g2, b2, a2c2, nullptr, nullptr, nullptr);
    k_out<<<512, 256, 0, stream>>>(hmax, hmin, a2c2, out);
}